// Round 10
// baseline (2928.340 us; speedup 1.0000x reference)
//
#include <hip/hip_runtime.h>
#include <math.h>

#define NT 262144
#define NS 512
#define ES 2097152
#define EO 8192
#define NLAYER 4
#define WROW 68         // LDS window row stride in floats (272B, 16B-aligned)
#define BSL 704         // per (sub,xcd) record-slice capacity (avg 512, +8.5 sigma)
#define EREG 8192       // per-subgraph padded CSR region (records)

typedef short bf16x8 __attribute__((ext_vector_type(8)));
typedef float f32x4 __attribute__((ext_vector_type(4)));
typedef _Float16 half8 __attribute__((ext_vector_type(8)));
typedef _Float16 half4v __attribute__((ext_vector_type(4)));

// hi/lo bf16 split of 8 floats -> packed MFMA operands.
__device__ __forceinline__ void cvt_hilo(const float* v, bf16x8* hi, bf16x8* lo) {
    union U { bf16x8 v; unsigned u[4]; };
    U H, L;
    #pragma unroll
    for (int q = 0; q < 4; q++) {
        float v0 = v[2 * q], v1 = v[2 * q + 1];
        unsigned h01;
        asm("v_cvt_pk_bf16_f32 %0, %1, %2" : "=v"(h01) : "v"(v0), "v"(v1));
        float l0 = v0 - __uint_as_float(h01 << 16);
        float l1 = v1 - __uint_as_float(h01 & 0xffff0000u);
        unsigned l01;
        asm("v_cvt_pk_bf16_f32 %0, %1, %2" : "=v"(l01) : "v"(l0), "v"(l1));
        H.u[q] = h01; L.u[q] = l01;
    }
    *hi = H.v; *lo = L.v;
}

// ---------------- stage 1: bucket edges by subgraph (XCD-sliced) ----------
__global__ __launch_bounds__(256) void bucket_kernel(const int* __restrict__ ei,
        int* __restrict__ gcur, unsigned* __restrict__ rbuf) {
    __shared__ int lcnt[512];
    __shared__ int lcur[512];
    int p = blockIdx.x;
    int g = p & 7;
    int base = p * 4096;
    int tid = threadIdx.x;
    for (int t = tid; t < 512; t += 256) lcnt[t] = 0;
    __syncthreads();
    int subs[16];
    unsigned recs[16];
    #pragma unroll
    for (int j = 0; j < 16; j++) {
        int e = base + j * 256 + tid;
        int d = ei[ES + e];
        int srcl = ei[e] & 511;
        subs[j] = d >> 9;
        recs[j] = (unsigned)srcl | ((unsigned)(d & 511) << 16);
        atomicAdd(&lcnt[subs[j]], 1);
    }
    __syncthreads();
    for (int t = tid; t < 512; t += 256) {
        int c = lcnt[t];
        lcur[t] = c ? atomicAdd(&gcur[g * 512 + t], c) : 0;
    }
    __syncthreads();
    #pragma unroll
    for (int j = 0; j < 16; j++) {
        int s = subs[j];
        int pos = atomicAdd(&lcur[s], 1);
        if (pos < BSL) rbuf[((size_t)s * 8 + g) * BSL + pos] = recs[j];
    }
}

// ---------------- stage 2: per-subgraph padded CSR in LDS ------------------
__global__ __launch_bounds__(512) void csr_sub_kernel(const int* __restrict__ gcur,
        const unsigned* __restrict__ rbuf, int* __restrict__ rowptr,
        unsigned short* __restrict__ ebuf) {
    __shared__ int sdeg[512];
    __shared__ int sscan[512];
    __shared__ int scur[512];
    __shared__ unsigned short erow[EREG];
    __shared__ int scnt[8];
    int s = blockIdx.x;
    int t = threadIdx.x;
    sdeg[t] = 0;
    if (t < 8) scnt[t] = min(gcur[t * 512 + s], BSL);
    unsigned* e32 = (unsigned*)erow;
    #pragma unroll
    for (int j = 0; j < 8; j++) e32[j * 512 + t] = 0x02000200u;   // sentinel 512
    __syncthreads();
    for (int g = 0; g < 8; g++) {
        int cg = scnt[g];
        const unsigned* rb = rbuf + ((size_t)s * 8 + g) * BSL;
        for (int i = t; i < cg; i += 512) atomicAdd(&sdeg[rb[i] >> 16], 1);
    }
    __syncthreads();
    int pdeg = (sdeg[t] + 3) & ~3;    // quad-pad each row
    sscan[t] = pdeg;
    __syncthreads();
    for (int off = 1; off < 512; off <<= 1) {
        int x = (t >= off) ? sscan[t - off] : 0;
        __syncthreads();
        sscan[t] += x;
        __syncthreads();
    }
    int excl = sscan[t] - pdeg;
    scur[t] = excl;
    rowptr[s * 513 + t] = s * EREG + excl;
    if (t == 511) rowptr[s * 513 + 512] = s * EREG + sscan[511];
    __syncthreads();
    for (int g = 0; g < 8; g++) {
        int cg = scnt[g];
        const unsigned* rb = rbuf + ((size_t)s * 8 + g) * BSL;
        for (int i = t; i < cg; i += 512) {
            unsigned rec = rb[i];
            int pos = atomicAdd(&scur[rec >> 16], 1);
            erow[pos] = (unsigned short)(rec & 511);
        }
    }
    __syncthreads();
    uint4* eo = (uint4*)(ebuf + (size_t)s * EREG);
    const uint4* ei4 = (const uint4*)erow;
    eo[t] = ei4[t];
    eo[t + 512] = ei4[t + 512];
}

// ---------------- CSR build (small graph) + weight transposes -------------
__global__ void small_csr_kernel(const int* __restrict__ oei, int* __restrict__ rowptrS,
                                 int* __restrict__ srcsS,
                                 const float* __restrict__ Wrel_s,
                                 const float* __restrict__ Wroot_s,
                                 float* __restrict__ WrT, float* __restrict__ WtT) {
    __shared__ int sdeg[NS];
    __shared__ int scur[NS];
    int t = threadIdx.x;
    if (t < NS) sdeg[t] = 0;
    __syncthreads();
    for (int e = t; e < EO; e += 1024) atomicAdd(&sdeg[oei[EO + e]], 1);
    __syncthreads();
    int myv = (t < NS) ? sdeg[t] : 0;
    __syncthreads();
    for (int off = 1; off < NS; off <<= 1) {
        int x = (t >= off && t < NS) ? sdeg[t - off] : 0;
        __syncthreads();
        if (t < NS) sdeg[t] += x;
        __syncthreads();
    }
    if (t < NS) {
        int excl = sdeg[t] - myv;
        rowptrS[t] = excl;
        scur[t] = excl;
        if (t == 0) rowptrS[NS] = EO;
    }
    __syncthreads();
    for (int e = t; e < EO; e += 1024) {
        int d = oei[EO + e];
        int pos = atomicAdd(&scur[d], 1);
        srcsS[pos] = oei[e];
    }
    // transpose all 4 layers' small-graph weights: WrT[l][k][c] = Wrel_s[l][c][k]
    for (int idx = t; idx < NLAYER * 4096; idx += 1024) {
        int layer = idx >> 12;
        int rem = idx & 4095;
        int cc = rem >> 6, kk = rem & 63;
        WrT[layer * 4096 + kk * 64 + cc] = Wrel_s[idx];
        WtT[layer * 4096 + kk * 64 + cc] = Wroot_s[idx];
    }
}

// ---------------- fused gconv: 512 blocks x 1024 threads (16 waves) -------
// R8 counters: VALU 22%, LDS ~30%, occupancy 20% (2 waves/SIMD) -> latency-
// bound. 16 waves in ONE block doubles TLP without touching the cache
// footprint (R4's thrash was 2 BLOCKS/CU = 2 windows; this is 1 window).
// Wave w: tile group tg=w>>2 (tiles tg*2, tg*2+1), row-subtile m=w&3.
// launch_bounds(1024,4) caps VGPR at 128 so all 16 waves co-reside.
__global__ __launch_bounds__(1024, 4) void gconv_sub_kernel(
    const float* __restrict__ xsrc,          // x (mode 0 window source)
    const _Float16* __restrict__ h1prev,     // h1 fp16 (mode 1 window source)
    const float* __restrict__ h2,            // raw small-gconv out, prev layer
    const float* __restrict__ stB, const float* __restrict__ stS,   // prev stats
    const float* __restrict__ gB, const float* __restrict__ bB,
    const float* __restrict__ gS, const float* __restrict__ bS,
    int mode,
    const int* __restrict__ rowptr, const unsigned short* __restrict__ ebuf,
    const float* __restrict__ Wr, const float* __restrict__ Wt,
    const float* __restrict__ br,
    _Float16* __restrict__ hout, float* __restrict__ stats,
    // distributed small-graph gconv (all waves, node p)
    const float* __restrict__ xsumIn, const int* __restrict__ rowptrS,
    const int* __restrict__ srcsS, const float* __restrict__ WrT,
    const float* __restrict__ WtT, const float* __restrict__ brS,
    float* __restrict__ h2out, float* __restrict__ statsS)
{
    extern __shared__ char smem[];
    int tid = threadIdx.x;

    float* Wn = (float*)smem;                       // 513 * WROW floats (row 512 = zeros)
    float* bnp = Wn + 513 * WROW;                   // 256 floats

    int p = blockIdx.x;
    int sub = p;                                    // sub%8 == blockIdx%8: XCD-local ebuf
    int w = tid >> 6;        // 0..15
    int l = tid & 63;
    int cl = l & 15;          // A row / B col / C col within subtile
    int kg = l >> 4;          // k-group (8 consecutive k)
    int kg8 = kg * 8;
    int tg = w >> 2;          // tile group: tiles tg*2 .. tg*2+1
    int m = w & 3;            // row-subtile (16 rows)

    // ---- BN params of previous layer (finalize fused) ----
    if (mode) {
        if (tid < 64) {
            int c = tid;
            float sb = 0.f, qb = 0.f, ss = 0.f, qs = 0.f;
            for (int r2 = 0; r2 < 32; r2++) {
                sb += stB[r2 * 128 + c];
                qb += stB[r2 * 128 + 64 + c];
                ss += stS[r2 * 128 + c];
                qs += stS[r2 * 128 + 64 + c];
            }
            float muB = sb * (1.f / 262144.f);
            float varB = qb * (1.f / 262144.f) - muB * muB;
            float scB = gB[c] * rsqrtf(varB + 1e-5f);
            bnp[c] = scB;
            bnp[64 + c] = bB[c] - muB * scB;
            float muS = ss * (1.f / 512.f);
            float varS = qs * (1.f / 512.f) - muS * muS;
            float scS = gS[c] * rsqrtf(varS + 1e-5f);
            bnp[128 + c] = scS;
            bnp[192 + c] = bS[c] - muS * scS;
        }
        __syncthreads();
    }

    // ---- window load (+ fused combine transform), fp32 LDS store ----
    if (mode) {
        int r0w = tid >> 3;                 // 0..127
        int c8 = (tid & 7) * 8;
        float4 sB0 = *(const float4*)(bnp + c8);
        float4 sB1 = *(const float4*)(bnp + c8 + 4);
        float4 hB0 = *(const float4*)(bnp + 64 + c8);
        float4 hB1 = *(const float4*)(bnp + 64 + c8 + 4);
        float4 sS0 = *(const float4*)(bnp + 128 + c8);
        float4 sS1 = *(const float4*)(bnp + 128 + c8 + 4);
        float4 hS0 = *(const float4*)(bnp + 192 + c8);
        float4 hS1 = *(const float4*)(bnp + 192 + c8 + 4);
        const _Float16* hb = h1prev + (size_t)sub * 512 * 64;
        #pragma unroll
        for (int k = 0; k < 4; k++) {
            int r = r0w + k * 128;
            half8 hv = *(const half8*)(hb + r * 64 + c8);
            float4 b0 = *(const float4*)(h2 + r * 64 + c8);
            float4 b1 = *(const float4*)(h2 + r * 64 + c8 + 4);
            float4 o0, o1;
            o0.x = fmaxf((float)hv[0] * sB0.x + hB0.x + b0.x * sS0.x + hS0.x, 0.f);
            o0.y = fmaxf((float)hv[1] * sB0.y + hB0.y + b0.y * sS0.y + hS0.y, 0.f);
            o0.z = fmaxf((float)hv[2] * sB0.z + hB0.z + b0.z * sS0.z + hS0.z, 0.f);
            o0.w = fmaxf((float)hv[3] * sB0.w + hB0.w + b0.w * sS0.w + hS0.w, 0.f);
            o1.x = fmaxf((float)hv[4] * sB1.x + hB1.x + b1.x * sS1.x + hS1.x, 0.f);
            o1.y = fmaxf((float)hv[5] * sB1.y + hB1.y + b1.y * sS1.y + hS1.y, 0.f);
            o1.z = fmaxf((float)hv[6] * sB1.z + hB1.z + b1.z * sS1.z + hS1.z, 0.f);
            o1.w = fmaxf((float)hv[7] * sB1.w + hB1.w + b1.w * sS1.w + hS1.w, 0.f);
            *(float4*)(Wn + r * WROW + c8) = o0;
            *(float4*)(Wn + r * WROW + c8 + 4) = o1;
        }
    } else {
        const float* srcbase = xsrc + (size_t)sub * 512 * 64;
        for (int idx = tid; idx < 512 * 16; idx += 1024) {
            int r = idx >> 4;
            int c4 = (idx & 15) * 4;
            float4 a = *(const float4*)(srcbase + r * 64 + c4);
            *(float4*)(Wn + r * WROW + c4) = a;
        }
    }
    if (tid < WROW) Wn[512 * WROW + tid] = 0.f;     // sentinel row

    // ---- B fragments: 4 col-subtiles x 4 k-chunks, hi/lo ----
    bf16x8 Bh[16], Bl[16];
    float bias0, bias1, bias2, bias3;
    #pragma unroll
    for (int c = 0; c < 4; c++) {
        int col = c * 16 + cl;
        #pragma unroll
        for (int ch = 0; ch < 4; ch++) {
            const float* mat = (ch < 2) ? Wr : Wt;
            int k = (ch & 1) * 32 + kg8;
            float vv[8];
            *(float4*)vv = *(const float4*)(mat + col * 64 + k);
            *(float4*)(vv + 4) = *(const float4*)(mat + col * 64 + k + 4);
            cvt_hilo(vv, &Bh[c * 4 + ch], &Bl[c * 4 + ch]);
        }
    }
    bias0 = br[cl];
    bias1 = br[16 + cl];
    bias2 = br[32 + cl];
    bias3 = br[48 + cl];

    const uint2* ebuf2 = (const uint2*)ebuf;
    __syncthreads();   // Wn ready

#define GATH1(qv) { \
        const float* pp = Wn + (qv) * WROW + kg8; \
        float4 tg0 = *(const float4*)(pp); \
        float4 tg1 = *(const float4*)(pp + 4); \
        float4 tg2 = *(const float4*)(pp + 32); \
        float4 tg3 = *(const float4*)(pp + 36); \
        a0.x += tg0.x; a0.y += tg0.y; a0.z += tg0.z; a0.w += tg0.w; \
        a1.x += tg1.x; a1.y += tg1.y; a1.z += tg1.z; a1.w += tg1.w; \
        a2.x += tg2.x; a2.y += tg2.y; a2.z += tg2.z; a2.w += tg2.w; \
        a3.x += tg3.x; a3.y += tg3.y; a3.z += tg3.z; a3.w += tg3.w; \
    }

#define DO_CHUNK(g0h, g1h, ch) { \
        float gg[8]; \
        *(float4*)gg = g0h; *(float4*)(gg + 4) = g1h; \
        bf16x8 ah, al; \
        cvt_hilo(gg, &ah, &al); \
        acc0 = __builtin_amdgcn_mfma_f32_16x16x32_bf16(ah, Bh[0 * 4 + ch], acc0, 0, 0, 0); \
        acc1 = __builtin_amdgcn_mfma_f32_16x16x32_bf16(ah, Bh[1 * 4 + ch], acc1, 0, 0, 0); \
        acc2 = __builtin_amdgcn_mfma_f32_16x16x32_bf16(ah, Bh[2 * 4 + ch], acc2, 0, 0, 0); \
        acc3 = __builtin_amdgcn_mfma_f32_16x16x32_bf16(ah, Bh[3 * 4 + ch], acc3, 0, 0, 0); \
        acc0 = __builtin_amdgcn_mfma_f32_16x16x32_bf16(al, Bh[0 * 4 + ch], acc0, 0, 0, 0); \
        acc1 = __builtin_amdgcn_mfma_f32_16x16x32_bf16(al, Bh[1 * 4 + ch], acc1, 0, 0, 0); \
        acc2 = __builtin_amdgcn_mfma_f32_16x16x32_bf16(al, Bh[2 * 4 + ch], acc2, 0, 0, 0); \
        acc3 = __builtin_amdgcn_mfma_f32_16x16x32_bf16(al, Bh[3 * 4 + ch], acc3, 0, 0, 0); \
        acc0 = __builtin_amdgcn_mfma_f32_16x16x32_bf16(ah, Bl[0 * 4 + ch], acc0, 0, 0, 0); \
        acc1 = __builtin_amdgcn_mfma_f32_16x16x32_bf16(ah, Bl[1 * 4 + ch], acc1, 0, 0, 0); \
        acc2 = __builtin_amdgcn_mfma_f32_16x16x32_bf16(ah, Bl[2 * 4 + ch], acc2, 0, 0, 0); \
        acc3 = __builtin_amdgcn_mfma_f32_16x16x32_bf16(ah, Bl[3 * 4 + ch], acc3, 0, 0, 0); \
    }

    // BN stats accumulated in registers across tiles; one atomic set at end.
    float s0 = 0.f, s1 = 0.f, s2 = 0.f, s3 = 0.f;
    float q0s = 0.f, q1s = 0.f, q2s = 0.f, q3s = 0.f;

    // ---- barrier-free tile loop (2 tiles per wave) ----
    for (int tt = 0; tt < 2; tt++) {
        int tile = tg * 2 + tt;
        int nb = sub * 512 + tile * 64;
        int row = tile * 64 + m * 16 + cl;
        int rpb = sub * 513;
        int e0q = rowptr[rpb + row] >> 2;
        int e1q = rowptr[rpb + row + 1] >> 2;

        float4 a0 = make_float4(0.f, 0.f, 0.f, 0.f);
        float4 a1 = a0, a2 = a0, a3 = a0;
        uint2 rr = make_uint2(0u, 0u);
        int u = e0q;
        if (u < e1q) rr = ebuf2[u];
        while (u < e1q) {
            uint2 cur = rr;
            ++u;
            if (u < e1q) rr = ebuf2[u];
            unsigned q0 = cur.x & 0xffffu;
            unsigned q1 = cur.x >> 16;
            unsigned q2 = cur.y & 0xffffu;
            unsigned q3 = cur.y >> 16;
            GATH1(q0);
            GATH1(q1);
            GATH1(q2);
            GATH1(q3);
        }

        // root-operand dims from own window row
        const float* wrow = Wn + (size_t)(tile * 64 + m * 16 + cl) * WROW + kg8;
        float4 r0 = *(const float4*)(wrow);
        float4 r1 = *(const float4*)(wrow + 4);
        float4 r2 = *(const float4*)(wrow + 32);
        float4 r3 = *(const float4*)(wrow + 36);

        f32x4 acc0, acc1, acc2, acc3;
        #pragma unroll
        for (int j = 0; j < 4; j++) {
            acc0[j] = bias0; acc1[j] = bias1; acc2[j] = bias2; acc3[j] = bias3;
        }
        DO_CHUNK(a0, a1, 0);
        DO_CHUNK(a2, a3, 1);
        DO_CHUNK(r0, r1, 2);
        DO_CHUNK(r2, r3, 3);

        // epilogue: fp16 store + accumulate BN stats (fp32) in registers
        int node0 = nb + m * 16 + kg * 4;
        #pragma unroll
        for (int j = 0; j < 4; j++) {
            float v0 = acc0[j], v1 = acc1[j], v2 = acc2[j], v3 = acc3[j];
            size_t rowb = (size_t)(node0 + j) * 64;
            hout[rowb + cl] = (_Float16)v0;
            hout[rowb + 16 + cl] = (_Float16)v1;
            hout[rowb + 32 + cl] = (_Float16)v2;
            hout[rowb + 48 + cl] = (_Float16)v3;
            s0 += v0; q0s += v0 * v0;
            s1 += v1; q1s += v1 * v1;
            s2 += v2; q2s += v2 * v2;
            s3 += v3; q3s += v3 * v3;
        }
    }

    // ---- stats flush (once per wave) ----
    s0 += __shfl_xor(s0, 16, 64); s0 += __shfl_xor(s0, 32, 64);
    s1 += __shfl_xor(s1, 16, 64); s1 += __shfl_xor(s1, 32, 64);
    s2 += __shfl_xor(s2, 16, 64); s2 += __shfl_xor(s2, 32, 64);
    s3 += __shfl_xor(s3, 16, 64); s3 += __shfl_xor(s3, 32, 64);
    q0s += __shfl_xor(q0s, 16, 64); q0s += __shfl_xor(q0s, 32, 64);
    q1s += __shfl_xor(q1s, 16, 64); q1s += __shfl_xor(q1s, 32, 64);
    q2s += __shfl_xor(q2s, 16, 64); q2s += __shfl_xor(q2s, 32, 64);
    q3s += __shfl_xor(q3s, 16, 64); q3s += __shfl_xor(q3s, 32, 64);
    if (kg == 0) {
        int rep = p & 31;
        atomicAdd(&stats[rep * 128 + cl], s0);
        atomicAdd(&stats[rep * 128 + 16 + cl], s1);
        atomicAdd(&stats[rep * 128 + 32 + cl], s2);
        atomicAdd(&stats[rep * 128 + 48 + cl], s3);
        atomicAdd(&stats[rep * 128 + 64 + cl], q0s);
        atomicAdd(&stats[rep * 128 + 80 + cl], q1s);
        atomicAdd(&stats[rep * 128 + 96 + cl], q2s);
        atomicAdd(&stats[rep * 128 + 112 + cl], q3s);
    }

    // ---- distributed small-graph gconv for node p: ALL 16 waves ----
    // Wn is dead after the tile loop -> reuse as scratch.
    __syncthreads();
    {
        float* aggP = Wn;            // [16][64] per-wave partial agg
        float* ownF = Wn + 1024;     // [64]
        float* oP   = Wn + 1088;     // [16][64] matvec partials
        int e0 = rowptrS[p], e1 = rowptrS[p + 1];
        float ap = 0.f;
        for (int e = e0 + w; e < e1; e += 16) ap += xsumIn[srcsS[e] * 64 + l];
        aggP[w * 64 + l] = ap;
        if (w == 0) ownF[l] = xsumIn[p * 64 + l];
        __syncthreads();
        if (tid < 64) {
            float s = 0.f;
            #pragma unroll
            for (int ww = 0; ww < 16; ww++) s += aggP[ww * 64 + tid];
            aggP[tid] = s;
        }
        __syncthreads();
        int c = tid & 63, kc = tid >> 6;         // kc 0..15, 4 k's each
        float op = 0.f;
        #pragma unroll
        for (int kk = 0; kk < 4; kk++) {
            int k = kc * 4 + kk;
            op += WrT[k * 64 + c] * aggP[k] + WtT[k * 64 + c] * ownF[k];
        }
        oP[kc * 64 + c] = op;
        __syncthreads();
        if (tid < 64) {
            float o = brS[tid];
            #pragma unroll
            for (int kk = 0; kk < 16; kk++) o += oP[kk * 64 + tid];
            h2out[p * 64 + tid] = o;
            int rep = p & 31;
            atomicAdd(&statsS[rep * 128 + tid], o);
            atomicAdd(&statsS[rep * 128 + 64 + tid], o * o);
        }
    }
#undef GATH1
#undef DO_CHUNK
}

// ---- xsum v2: slab-sequential read + light atomic reduce ------------------
// Block g streams subgraphs 2g, 2g+1 CONTIGUOUSLY (vs old 32KB-strided row
// walk), applies the BN+relu transform, and atomicAdds its per-row
// contribution (x 1/512) into the zeroed xsum. 256 blocks = 1 full round;
// 8.4M coalesced float atomics (~64 adds/address).
__global__ __launch_bounds__(512) void xsum_kernel(
    const float* __restrict__ xsrc, const _Float16* __restrict__ h1prev,
    const float* __restrict__ h2,
    const float* __restrict__ stB, const float* __restrict__ stS,
    const float* __restrict__ gB, const float* __restrict__ bB,
    const float* __restrict__ gS, const float* __restrict__ bS,
    int mode, float* __restrict__ xsum)
{
    __shared__ float bnp[256];
    int t = threadIdx.x;
    if (mode) {
        if (t < 64) {
            int c = t;
            float sb = 0.f, qb = 0.f, ss = 0.f, qs = 0.f;
            for (int r2 = 0; r2 < 32; r2++) {
                sb += stB[r2 * 128 + c];
                qb += stB[r2 * 128 + 64 + c];
                ss += stS[r2 * 128 + c];
                qs += stS[r2 * 128 + 64 + c];
            }
            float muB = sb * (1.f / 262144.f);
            float varB = qb * (1.f / 262144.f) - muB * muB;
            float scB = gB[c] * rsqrtf(varB + 1e-5f);
            bnp[c] = scB;
            bnp[64 + c] = bB[c] - muB * scB;
            float muS = ss * (1.f / 512.f);
            float varS = qs * (1.f / 512.f) - muS * muS;
            float scS = gS[c] * rsqrtf(varS + 1e-5f);
            bnp[128 + c] = scS;
            bnp[192 + c] = bS[c] - muS * scS;
        }
        __syncthreads();
    }

    int g = blockIdx.x;            // subgraphs 2g, 2g+1
    int w = t >> 6;                // wave: rows w*64 .. w*64+63
    int l = t & 63;
    int ro = l >> 3;               // row offset 0..7
    int c8 = (l & 7) * 8;          // dim base

    float sB[8], hB[8], sS8[8], hS8[8];
    if (mode) {
        #pragma unroll
        for (int k = 0; k < 8; k++) {
            sB[k] = bnp[c8 + k];
            hB[k] = bnp[64 + c8 + k];
            sS8[k] = bnp[128 + c8 + k];
            hS8[k] = bnp[192 + c8 + k];
        }
    }

    for (int rb = 0; rb < 8; rb++) {
        int r = w * 64 + rb * 8 + ro;
        float acc[8];
        #pragma unroll
        for (int k = 0; k < 8; k++) acc[k] = 0.f;
        if (mode) {
            float bx[8];
            float4 b0 = *(const float4*)(h2 + r * 64 + c8);
            float4 b1 = *(const float4*)(h2 + r * 64 + c8 + 4);
            bx[0] = b0.x * sS8[0] + hS8[0]; bx[1] = b0.y * sS8[1] + hS8[1];
            bx[2] = b0.z * sS8[2] + hS8[2]; bx[3] = b0.w * sS8[3] + hS8[3];
            bx[4] = b1.x * sS8[4] + hS8[4]; bx[5] = b1.y * sS8[5] + hS8[5];
            bx[6] = b1.z * sS8[6] + hS8[6]; bx[7] = b1.w * sS8[7] + hS8[7];
            #pragma unroll
            for (int j = 0; j < 2; j++) {
                size_t base = ((size_t)((g * 2 + j) * 512 + r)) * 64 + c8;
                half8 hv = *(const half8*)(h1prev + base);
                #pragma unroll
                for (int k = 0; k < 8; k++)
                    acc[k] += fmaxf((float)hv[k] * sB[k] + hB[k] + bx[k], 0.f);
            }
        } else {
            #pragma unroll
            for (int j = 0; j < 2; j++) {
                size_t base = ((size_t)((g * 2 + j) * 512 + r)) * 64 + c8;
                float4 a0 = *(const float4*)(xsrc + base);
                float4 a1 = *(const float4*)(xsrc + base + 4);
                acc[0] += a0.x; acc[1] += a0.y; acc[2] += a0.z; acc[3] += a0.w;
                acc[4] += a1.x; acc[5] += a1.y; acc[6] += a1.z; acc[7] += a1.w;
            }
        }
        #pragma unroll
        for (int k = 0; k < 8; k++)
            atomicAdd(&xsum[r * 64 + c8 + k], acc[k] * (1.f / 512.f));
    }
}

// ---------------- head ----------------
__global__ void head_kernel(const float* __restrict__ xs, const float* __restrict__ W1,
                            const float* __restrict__ b1, const float* __restrict__ W2,
                            const float* __restrict__ b2, float* __restrict__ out) {
    __shared__ float z[64];
    __shared__ float hid[128];
    int t = threadIdx.x;
    int n = blockIdx.x;
    if (t < 64) {
        float v = xs[n * 64 + t];
        float m = v;
        for (int off = 32; off >= 1; off >>= 1) m = fmaxf(m, __shfl_xor(m, off, 64));
        float e = expf(v - m);
        float s = e;
        for (int off = 32; off >= 1; off >>= 1) s += __shfl_xor(s, off, 64);
        z[t] = v - m - logf(s);
    }
    __syncthreads();
    {
        float acc = b1[t];
        const float* wrow = W1 + t * 64;
        #pragma unroll 8
        for (int k = 0; k < 64; k++) acc += z[k] * wrow[k];
        hid[t] = fmaxf(acc, 0.f);
    }
    __syncthreads();
    if (t < 10) {
        float o = b2[t];
        const float* wrow = W2 + t * 128;
        #pragma unroll 8
        for (int j = 0; j < 128; j++) o += hid[j] * wrow[j];
        out[n * 10 + t] = o;
    }
}

extern "C" void kernel_launch(void* const* d_in, const int* in_sizes, int n_in,
                              void* d_out, int out_size, void* d_ws, size_t ws_size,
                              hipStream_t stream) {
    const float* x       = (const float*)d_in[0];
    const float* Wrel    = (const float*)d_in[1];
    const float* brel    = (const float*)d_in[2];
    const float* Wroot   = (const float*)d_in[3];
    const float* bn_g    = (const float*)d_in[4];
    const float* bn_b    = (const float*)d_in[5];
    const float* Wrel_s  = (const float*)d_in[6];
    const float* brel_s  = (const float*)d_in[7];
    const float* Wroot_s = (const float*)d_in[8];
    const float* bns_g   = (const float*)d_in[9];
    const float* bns_b   = (const float*)d_in[10];
    const float* W1      = (const float*)d_in[11];
    const float* b1      = (const float*)d_in[12];
    const float* W2      = (const float*)d_in[13];
    const float* b2      = (const float*)d_in[14];
    const int* ei        = (const int*)d_in[15];
    const int* oei       = (const int*)d_in[16];
    float* out = (float*)d_out;

    char* ws = (char*)d_ws;
    size_t off = 0;
    auto alloc = [&](size_t bytes) -> void* {
        void* p = ws + off;
        off = (off + bytes + 255) & ~(size_t)255;
        return p;
    };
    _Float16* h1b = (_Float16*)alloc((size_t)NT * 64 * 2);   // h1 in fp16 (32 MB)
    float* xsum  = (float*)alloc(NS * 64 * 4);
    float* h2buf = (float*)alloc((size_t)2 * NS * 64 * 4);   // ping-pong
    float* stats = (float*)alloc(NLAYER * 2 * 4096 * 4);
    int* rowptr  = (int*)alloc((size_t)NS * 513 * 4);
    int* gcur    = (int*)alloc(8 * 512 * 4);
    unsigned short* ebuf = (unsigned short*)alloc((size_t)NS * EREG * 2);
    int* rowptrS = (int*)alloc(513 * 4);
    int* srcsS   = (int*)alloc(EO * 4);
    float* wrTs  = (float*)alloc(NLAYER * 4096 * 4);
    float* wtTs  = (float*)alloc(NLAYER * 4096 * 4);
    // rbuf (bucketed records) aliases h1b: consumed by csr_sub before layer 0
    unsigned* rbuf = (unsigned*)h1b;   // needs 512*8*BSL*4 = 11.5 MB < 32 MB
    (void)ws_size; (void)in_sizes; (void)n_in; (void)out_size;

    hipMemsetAsync(gcur, 0, 8 * 512 * 4, stream);
    hipMemsetAsync(stats, 0, (size_t)NLAYER * 2 * 4096 * 4, stream);

    bucket_kernel<<<ES / 4096, 256, 0, stream>>>(ei, gcur, rbuf);
    csr_sub_kernel<<<NS, 512, 0, stream>>>(gcur, rbuf, rowptr, ebuf);
    small_csr_kernel<<<1, 1024, 0, stream>>>(oei, rowptrS, srcsS,
                                             Wrel_s, Wroot_s, wrTs, wtTs);

    // fp32 window: 513*68 + 256 floats = 140548 B -> 1 block/CU
    const size_t SMEM = (513 * WROW + 256) * 4;

    for (int i = 0; i < NLAYER; i++) {
        int mode = (i > 0);
        const float* h2R = h2buf + (size_t)((i - 1) & 1) * NS * 64;  // prev (i>0)
        float* h2W = h2buf + (size_t)(i & 1) * NS * 64;
        const float* stPB = stats + (i - 1) * 8192;        // prev layer stats
        const float* stPS = stPB + 4096;
        const float* gBp = bn_g + (i - 1) * 64;
        const float* bBp = bn_b + (i - 1) * 64;
        const float* gSp = bns_g + (i - 1) * 64;
        const float* bSp = bns_b + (i - 1) * 64;
        float* stB = stats + i * 8192;
        float* stS = stB + 4096;

        hipMemsetAsync(xsum, 0, NS * 64 * 4, stream);
        xsum_kernel<<<NS / 2, 512, 0, stream>>>(x, h1b, h2R, stPB, stPS,
                                                gBp, bBp, gSp, bSp, mode, xsum);
        gconv_sub_kernel<<<NS, 1024, SMEM, stream>>>(x, h1b, h2R, stPB, stPS,
            gBp, bBp, gSp, bSp, mode, rowptr, ebuf,
            Wrel + i * 4096, Wroot + i * 4096, brel + i * 64, h1b, stB,
            xsum, rowptrS, srcsS,
            wrTs + i * 4096, wtTs + i * 4096, brel_s + i * 64, h2W, stS);
    }
    // final xsum = smean(h_final) from h1(3), stats(3), h2(3)
    {
        const float* stPB = stats + 3 * 8192;
        const float* stPS = stPB + 4096;
        const float* h2R = h2buf + (size_t)(3 & 1) * NS * 64;
        hipMemsetAsync(xsum, 0, NS * 64 * 4, stream);
        xsum_kernel<<<NS / 2, 512, 0, stream>>>(x, h1b, h2R, stPB, stPS,
            bn_g + 3 * 64, bn_b + 3 * 64, bns_g + 3 * 64, bns_b + 3 * 64, 1, xsum);
    }
    head_kernel<<<NS, 128, 0, stream>>>(xsum, W1, b1, W2, b2, out);
}

// Round 11
// 481.876 us; speedup vs baseline: 6.0770x; 6.0770x over previous
//
#include <hip/hip_runtime.h>
#include <math.h>

#define NT 262144
#define NS 512
#define ES 2097152
#define EO 8192
#define NLAYER 4
#define WROW 68         // LDS window row stride in floats (272B, 16B-aligned)
#define BSL 704         // per (sub,xcd) record-slice capacity (avg 512, +8.5 sigma)
#define EREG 8192       // per-subgraph padded CSR region (records)
#define H1S (520 * 64)  // fp16 elems per h1 subgraph slab: 8 pad rows -> 66560B
                        // stride (non-pow2) kills HBM channel aliasing on xsum's
                        // per-subgraph gather (R8's 64KB stride ran ~1 TB/s)

typedef short bf16x8 __attribute__((ext_vector_type(8)));
typedef float f32x4 __attribute__((ext_vector_type(4)));
typedef _Float16 half8 __attribute__((ext_vector_type(8)));
typedef _Float16 half4v __attribute__((ext_vector_type(4)));

// hi/lo bf16 split of 8 floats -> packed MFMA operands.
__device__ __forceinline__ void cvt_hilo(const float* v, bf16x8* hi, bf16x8* lo) {
    union U { bf16x8 v; unsigned u[4]; };
    U H, L;
    #pragma unroll
    for (int q = 0; q < 4; q++) {
        float v0 = v[2 * q], v1 = v[2 * q + 1];
        unsigned h01;
        asm("v_cvt_pk_bf16_f32 %0, %1, %2" : "=v"(h01) : "v"(v0), "v"(v1));
        float l0 = v0 - __uint_as_float(h01 << 16);
        float l1 = v1 - __uint_as_float(h01 & 0xffff0000u);
        unsigned l01;
        asm("v_cvt_pk_bf16_f32 %0, %1, %2" : "=v"(l01) : "v"(l0), "v"(l1));
        H.u[q] = h01; L.u[q] = l01;
    }
    *hi = H.v; *lo = L.v;
}

// ---------------- stage 1: bucket edges by subgraph (XCD-sliced) ----------
__global__ __launch_bounds__(256) void bucket_kernel(const int* __restrict__ ei,
        int* __restrict__ gcur, unsigned* __restrict__ rbuf) {
    __shared__ int lcnt[512];
    __shared__ int lcur[512];
    int p = blockIdx.x;
    int g = p & 7;
    int base = p * 4096;
    int tid = threadIdx.x;
    for (int t = tid; t < 512; t += 256) lcnt[t] = 0;
    __syncthreads();
    int subs[16];
    unsigned recs[16];
    #pragma unroll
    for (int j = 0; j < 16; j++) {
        int e = base + j * 256 + tid;
        int d = ei[ES + e];
        int srcl = ei[e] & 511;
        subs[j] = d >> 9;
        recs[j] = (unsigned)srcl | ((unsigned)(d & 511) << 16);
        atomicAdd(&lcnt[subs[j]], 1);
    }
    __syncthreads();
    for (int t = tid; t < 512; t += 256) {
        int c = lcnt[t];
        lcur[t] = c ? atomicAdd(&gcur[g * 512 + t], c) : 0;
    }
    __syncthreads();
    #pragma unroll
    for (int j = 0; j < 16; j++) {
        int s = subs[j];
        int pos = atomicAdd(&lcur[s], 1);
        if (pos < BSL) rbuf[((size_t)s * 8 + g) * BSL + pos] = recs[j];
    }
}

// ---------------- stage 2: per-subgraph padded CSR in LDS ------------------
__global__ __launch_bounds__(512) void csr_sub_kernel(const int* __restrict__ gcur,
        const unsigned* __restrict__ rbuf, int* __restrict__ rowptr,
        unsigned short* __restrict__ ebuf) {
    __shared__ int sdeg[512];
    __shared__ int sscan[512];
    __shared__ int scur[512];
    __shared__ unsigned short erow[EREG];
    __shared__ int scnt[8];
    int s = blockIdx.x;
    int t = threadIdx.x;
    sdeg[t] = 0;
    if (t < 8) scnt[t] = min(gcur[t * 512 + s], BSL);
    unsigned* e32 = (unsigned*)erow;
    #pragma unroll
    for (int j = 0; j < 8; j++) e32[j * 512 + t] = 0x02000200u;   // sentinel 512
    __syncthreads();
    for (int g = 0; g < 8; g++) {
        int cg = scnt[g];
        const unsigned* rb = rbuf + ((size_t)s * 8 + g) * BSL;
        for (int i = t; i < cg; i += 512) atomicAdd(&sdeg[rb[i] >> 16], 1);
    }
    __syncthreads();
    int pdeg = (sdeg[t] + 3) & ~3;    // quad-pad each row
    sscan[t] = pdeg;
    __syncthreads();
    for (int off = 1; off < 512; off <<= 1) {
        int x = (t >= off) ? sscan[t - off] : 0;
        __syncthreads();
        sscan[t] += x;
        __syncthreads();
    }
    int excl = sscan[t] - pdeg;
    scur[t] = excl;
    rowptr[s * 513 + t] = s * EREG + excl;
    if (t == 511) rowptr[s * 513 + 512] = s * EREG + sscan[511];
    __syncthreads();
    for (int g = 0; g < 8; g++) {
        int cg = scnt[g];
        const unsigned* rb = rbuf + ((size_t)s * 8 + g) * BSL;
        for (int i = t; i < cg; i += 512) {
            unsigned rec = rb[i];
            int pos = atomicAdd(&scur[rec >> 16], 1);
            erow[pos] = (unsigned short)(rec & 511);
        }
    }
    __syncthreads();
    uint4* eo = (uint4*)(ebuf + (size_t)s * EREG);
    const uint4* ei4 = (const uint4*)erow;
    eo[t] = ei4[t];
    eo[t + 512] = ei4[t + 512];
}

// ---------------- CSR build (small graph) + weight transposes -------------
__global__ void small_csr_kernel(const int* __restrict__ oei, int* __restrict__ rowptrS,
                                 int* __restrict__ srcsS,
                                 const float* __restrict__ Wrel_s,
                                 const float* __restrict__ Wroot_s,
                                 float* __restrict__ WrT, float* __restrict__ WtT) {
    __shared__ int sdeg[NS];
    __shared__ int scur[NS];
    int t = threadIdx.x;
    if (t < NS) sdeg[t] = 0;
    __syncthreads();
    for (int e = t; e < EO; e += 1024) atomicAdd(&sdeg[oei[EO + e]], 1);
    __syncthreads();
    int myv = (t < NS) ? sdeg[t] : 0;
    __syncthreads();
    for (int off = 1; off < NS; off <<= 1) {
        int x = (t >= off && t < NS) ? sdeg[t - off] : 0;
        __syncthreads();
        if (t < NS) sdeg[t] += x;
        __syncthreads();
    }
    if (t < NS) {
        int excl = sdeg[t] - myv;
        rowptrS[t] = excl;
        scur[t] = excl;
        if (t == 0) rowptrS[NS] = EO;
    }
    __syncthreads();
    for (int e = t; e < EO; e += 1024) {
        int d = oei[EO + e];
        int pos = atomicAdd(&scur[d], 1);
        srcsS[pos] = oei[e];
    }
    // transpose all 4 layers' small-graph weights: WrT[l][k][c] = Wrel_s[l][c][k]
    for (int idx = t; idx < NLAYER * 4096; idx += 1024) {
        int layer = idx >> 12;
        int rem = idx & 4095;
        int cc = rem >> 6, kk = rem & 63;
        WrT[layer * 4096 + kk * 64 + cc] = Wrel_s[idx];
        WtT[layer * 4096 + kk * 64 + cc] = Wroot_s[idx];
    }
}

// ---------------- fused gconv: 512 blocks x 512 threads (R8 config -------
// verified 66us; R9's 1024-thread/(1024,4) variant spilled B-fragments).
// h1 fp16 in PADDED slabs (stride H1S). fp32 LDS window. All-wave
// distributed small-graph gconv tail reusing dead window LDS.
__global__ __launch_bounds__(512, 2) void gconv_sub_kernel(
    const float* __restrict__ xsrc,          // x (mode 0 window source)
    const _Float16* __restrict__ h1prev,     // h1 fp16 padded slabs (mode 1)
    const float* __restrict__ h2,            // raw small-gconv out, prev layer
    const float* __restrict__ stB, const float* __restrict__ stS,   // prev stats
    const float* __restrict__ gB, const float* __restrict__ bB,
    const float* __restrict__ gS, const float* __restrict__ bS,
    int mode,
    const int* __restrict__ rowptr, const unsigned short* __restrict__ ebuf,
    const float* __restrict__ Wr, const float* __restrict__ Wt,
    const float* __restrict__ br,
    _Float16* __restrict__ hout, float* __restrict__ stats,
    // distributed small-graph gconv (all waves, node p)
    const float* __restrict__ xsumIn, const int* __restrict__ rowptrS,
    const int* __restrict__ srcsS, const float* __restrict__ WrT,
    const float* __restrict__ WtT, const float* __restrict__ brS,
    float* __restrict__ h2out, float* __restrict__ statsS)
{
    extern __shared__ char smem[];
    int tid = threadIdx.x;

    float* Wn = (float*)smem;                       // 513 * WROW floats (row 512 = zeros)
    float* bnp = Wn + 513 * WROW;                   // 256 floats

    int p = blockIdx.x;
    int sub = p;                                    // sub%8 == blockIdx%8: XCD-local ebuf
    int w = tid >> 6;
    int l = tid & 63;
    int cl = l & 15;          // A row / B col / C col within subtile
    int kg = l >> 4;          // k-group (8 consecutive k)
    int kg8 = kg * 8;
    int half = w >> 2;        // tile-half: waves 0-3 -> tiles 0-3, 4-7 -> 4-7
    int m = w & 3;            // row-subtile (16 rows)

    // ---- BN params of previous layer (finalize fused) ----
    if (mode) {
        if (tid < 64) {
            int c = tid;
            float sb = 0.f, qb = 0.f, ss = 0.f, qs = 0.f;
            for (int r2 = 0; r2 < 32; r2++) {
                sb += stB[r2 * 128 + c];
                qb += stB[r2 * 128 + 64 + c];
                ss += stS[r2 * 128 + c];
                qs += stS[r2 * 128 + 64 + c];
            }
            float muB = sb * (1.f / 262144.f);
            float varB = qb * (1.f / 262144.f) - muB * muB;
            float scB = gB[c] * rsqrtf(varB + 1e-5f);
            bnp[c] = scB;
            bnp[64 + c] = bB[c] - muB * scB;
            float muS = ss * (1.f / 512.f);
            float varS = qs * (1.f / 512.f) - muS * muS;
            float scS = gS[c] * rsqrtf(varS + 1e-5f);
            bnp[128 + c] = scS;
            bnp[192 + c] = bS[c] - muS * scS;
        }
        __syncthreads();
    }

    // ---- window load (+ fused combine transform), fp32 LDS store ----
    if (mode) {
        int r0w = tid >> 3;
        int c8 = (tid & 7) * 8;
        float4 sB0 = *(const float4*)(bnp + c8);
        float4 sB1 = *(const float4*)(bnp + c8 + 4);
        float4 hB0 = *(const float4*)(bnp + 64 + c8);
        float4 hB1 = *(const float4*)(bnp + 64 + c8 + 4);
        float4 sS0 = *(const float4*)(bnp + 128 + c8);
        float4 sS1 = *(const float4*)(bnp + 128 + c8 + 4);
        float4 hS0 = *(const float4*)(bnp + 192 + c8);
        float4 hS1 = *(const float4*)(bnp + 192 + c8 + 4);
        const _Float16* hb = h1prev + (size_t)sub * H1S;
        #pragma unroll
        for (int k = 0; k < 8; k++) {
            int r = r0w + k * 64;
            half8 hv = *(const half8*)(hb + r * 64 + c8);
            float4 b0 = *(const float4*)(h2 + r * 64 + c8);
            float4 b1 = *(const float4*)(h2 + r * 64 + c8 + 4);
            float4 o0, o1;
            o0.x = fmaxf((float)hv[0] * sB0.x + hB0.x + b0.x * sS0.x + hS0.x, 0.f);
            o0.y = fmaxf((float)hv[1] * sB0.y + hB0.y + b0.y * sS0.y + hS0.y, 0.f);
            o0.z = fmaxf((float)hv[2] * sB0.z + hB0.z + b0.z * sS0.z + hS0.z, 0.f);
            o0.w = fmaxf((float)hv[3] * sB0.w + hB0.w + b0.w * sS0.w + hS0.w, 0.f);
            o1.x = fmaxf((float)hv[4] * sB1.x + hB1.x + b1.x * sS1.x + hS1.x, 0.f);
            o1.y = fmaxf((float)hv[5] * sB1.y + hB1.y + b1.y * sS1.y + hS1.y, 0.f);
            o1.z = fmaxf((float)hv[6] * sB1.z + hB1.z + b1.z * sS1.z + hS1.z, 0.f);
            o1.w = fmaxf((float)hv[7] * sB1.w + hB1.w + b1.w * sS1.w + hS1.w, 0.f);
            *(float4*)(Wn + r * WROW + c8) = o0;
            *(float4*)(Wn + r * WROW + c8 + 4) = o1;
        }
    } else {
        const float* srcbase = xsrc + (size_t)sub * 512 * 64;
        for (int idx = tid; idx < 512 * 16; idx += 512) {
            int r = idx >> 4;
            int c4 = (idx & 15) * 4;
            float4 a = *(const float4*)(srcbase + r * 64 + c4);
            *(float4*)(Wn + r * WROW + c4) = a;
        }
    }
    if (tid < WROW) Wn[512 * WROW + tid] = 0.f;     // sentinel row

    // ---- B fragments: 4 col-subtiles x 4 k-chunks, hi/lo ----
    bf16x8 Bh[16], Bl[16];
    float bias0, bias1, bias2, bias3;
    #pragma unroll
    for (int c = 0; c < 4; c++) {
        int col = c * 16 + cl;
        #pragma unroll
        for (int ch = 0; ch < 4; ch++) {
            const float* mat = (ch < 2) ? Wr : Wt;
            int k = (ch & 1) * 32 + kg8;
            float vv[8];
            *(float4*)vv = *(const float4*)(mat + col * 64 + k);
            *(float4*)(vv + 4) = *(const float4*)(mat + col * 64 + k + 4);
            cvt_hilo(vv, &Bh[c * 4 + ch], &Bl[c * 4 + ch]);
        }
    }
    bias0 = br[cl];
    bias1 = br[16 + cl];
    bias2 = br[32 + cl];
    bias3 = br[48 + cl];

    const uint2* ebuf2 = (const uint2*)ebuf;
    __syncthreads();   // Wn ready

#define GATH1(qv) { \
        const float* pp = Wn + (qv) * WROW + kg8; \
        float4 tg0 = *(const float4*)(pp); \
        float4 tg1 = *(const float4*)(pp + 4); \
        float4 tg2 = *(const float4*)(pp + 32); \
        float4 tg3 = *(const float4*)(pp + 36); \
        a0.x += tg0.x; a0.y += tg0.y; a0.z += tg0.z; a0.w += tg0.w; \
        a1.x += tg1.x; a1.y += tg1.y; a1.z += tg1.z; a1.w += tg1.w; \
        a2.x += tg2.x; a2.y += tg2.y; a2.z += tg2.z; a2.w += tg2.w; \
        a3.x += tg3.x; a3.y += tg3.y; a3.z += tg3.z; a3.w += tg3.w; \
    }

#define DO_CHUNK(g0h, g1h, ch) { \
        float gg[8]; \
        *(float4*)gg = g0h; *(float4*)(gg + 4) = g1h; \
        bf16x8 ah, al; \
        cvt_hilo(gg, &ah, &al); \
        acc0 = __builtin_amdgcn_mfma_f32_16x16x32_bf16(ah, Bh[0 * 4 + ch], acc0, 0, 0, 0); \
        acc1 = __builtin_amdgcn_mfma_f32_16x16x32_bf16(ah, Bh[1 * 4 + ch], acc1, 0, 0, 0); \
        acc2 = __builtin_amdgcn_mfma_f32_16x16x32_bf16(ah, Bh[2 * 4 + ch], acc2, 0, 0, 0); \
        acc3 = __builtin_amdgcn_mfma_f32_16x16x32_bf16(ah, Bh[3 * 4 + ch], acc3, 0, 0, 0); \
        acc0 = __builtin_amdgcn_mfma_f32_16x16x32_bf16(al, Bh[0 * 4 + ch], acc0, 0, 0, 0); \
        acc1 = __builtin_amdgcn_mfma_f32_16x16x32_bf16(al, Bh[1 * 4 + ch], acc1, 0, 0, 0); \
        acc2 = __builtin_amdgcn_mfma_f32_16x16x32_bf16(al, Bh[2 * 4 + ch], acc2, 0, 0, 0); \
        acc3 = __builtin_amdgcn_mfma_f32_16x16x32_bf16(al, Bh[3 * 4 + ch], acc3, 0, 0, 0); \
        acc0 = __builtin_amdgcn_mfma_f32_16x16x32_bf16(ah, Bl[0 * 4 + ch], acc0, 0, 0, 0); \
        acc1 = __builtin_amdgcn_mfma_f32_16x16x32_bf16(ah, Bl[1 * 4 + ch], acc1, 0, 0, 0); \
        acc2 = __builtin_amdgcn_mfma_f32_16x16x32_bf16(ah, Bl[2 * 4 + ch], acc2, 0, 0, 0); \
        acc3 = __builtin_amdgcn_mfma_f32_16x16x32_bf16(ah, Bl[3 * 4 + ch], acc3, 0, 0, 0); \
    }

    // BN stats accumulated in registers across tiles; one atomic set at end.
    float s0 = 0.f, s1 = 0.f, s2 = 0.f, s3 = 0.f;
    float q0s = 0.f, q1s = 0.f, q2s = 0.f, q3s = 0.f;

    // ---- barrier-free tile loop (4 tiles per wave) ----
    for (int tt = 0; tt < 4; tt++) {
        int tile = half * 4 + tt;
        int row = tile * 64 + m * 16 + cl;
        int rpb = sub * 513;
        int e0q = rowptr[rpb + row] >> 2;
        int e1q = rowptr[rpb + row + 1] >> 2;

        float4 a0 = make_float4(0.f, 0.f, 0.f, 0.f);
        float4 a1 = a0, a2 = a0, a3 = a0;
        uint2 rr = make_uint2(0u, 0u);
        int u = e0q;
        if (u < e1q) rr = ebuf2[u];
        while (u < e1q) {
            uint2 cur = rr;
            ++u;
            if (u < e1q) rr = ebuf2[u];
            unsigned q0 = cur.x & 0xffffu;
            unsigned q1 = cur.x >> 16;
            unsigned q2 = cur.y & 0xffffu;
            unsigned q3 = cur.y >> 16;
            GATH1(q0);
            GATH1(q1);
            GATH1(q2);
            GATH1(q3);
        }

        // root-operand dims from own window row
        const float* wrow = Wn + (size_t)(tile * 64 + m * 16 + cl) * WROW + kg8;
        float4 r0 = *(const float4*)(wrow);
        float4 r1 = *(const float4*)(wrow + 4);
        float4 r2 = *(const float4*)(wrow + 32);
        float4 r3 = *(const float4*)(wrow + 36);

        f32x4 acc0, acc1, acc2, acc3;
        #pragma unroll
        for (int j = 0; j < 4; j++) {
            acc0[j] = bias0; acc1[j] = bias1; acc2[j] = bias2; acc3[j] = bias3;
        }
        DO_CHUNK(a0, a1, 0);
        DO_CHUNK(a2, a3, 1);
        DO_CHUNK(r0, r1, 2);
        DO_CHUNK(r2, r3, 3);

        // epilogue: fp16 store (padded slab) + BN stats in registers
        int nodeL0 = tile * 64 + m * 16 + kg * 4;
        #pragma unroll
        for (int j = 0; j < 4; j++) {
            float v0 = acc0[j], v1 = acc1[j], v2 = acc2[j], v3 = acc3[j];
            size_t rowb = (size_t)sub * H1S + (size_t)(nodeL0 + j) * 64;
            hout[rowb + cl] = (_Float16)v0;
            hout[rowb + 16 + cl] = (_Float16)v1;
            hout[rowb + 32 + cl] = (_Float16)v2;
            hout[rowb + 48 + cl] = (_Float16)v3;
            s0 += v0; q0s += v0 * v0;
            s1 += v1; q1s += v1 * v1;
            s2 += v2; q2s += v2 * v2;
            s3 += v3; q3s += v3 * v3;
        }
    }

    // ---- stats flush (once per wave) ----
    s0 += __shfl_xor(s0, 16, 64); s0 += __shfl_xor(s0, 32, 64);
    s1 += __shfl_xor(s1, 16, 64); s1 += __shfl_xor(s1, 32, 64);
    s2 += __shfl_xor(s2, 16, 64); s2 += __shfl_xor(s2, 32, 64);
    s3 += __shfl_xor(s3, 16, 64); s3 += __shfl_xor(s3, 32, 64);
    q0s += __shfl_xor(q0s, 16, 64); q0s += __shfl_xor(q0s, 32, 64);
    q1s += __shfl_xor(q1s, 16, 64); q1s += __shfl_xor(q1s, 32, 64);
    q2s += __shfl_xor(q2s, 16, 64); q2s += __shfl_xor(q2s, 32, 64);
    q3s += __shfl_xor(q3s, 16, 64); q3s += __shfl_xor(q3s, 32, 64);
    if (kg == 0) {
        int rep = p & 31;
        atomicAdd(&stats[rep * 128 + cl], s0);
        atomicAdd(&stats[rep * 128 + 16 + cl], s1);
        atomicAdd(&stats[rep * 128 + 32 + cl], s2);
        atomicAdd(&stats[rep * 128 + 48 + cl], s3);
        atomicAdd(&stats[rep * 128 + 64 + cl], q0s);
        atomicAdd(&stats[rep * 128 + 80 + cl], q1s);
        atomicAdd(&stats[rep * 128 + 96 + cl], q2s);
        atomicAdd(&stats[rep * 128 + 112 + cl], q3s);
    }

    // ---- distributed small-graph gconv for node p: ALL 8 waves ----
    __syncthreads();
    {
        float* aggP = Wn;            // [8][64] per-wave partial agg
        float* ownF = Wn + 512;      // [64]
        float* oP   = Wn + 576;      // [8][64] matvec partials
        int e0 = rowptrS[p], e1 = rowptrS[p + 1];
        float ap = 0.f;
        for (int e = e0 + w; e < e1; e += 8) ap += xsumIn[srcsS[e] * 64 + l];
        aggP[w * 64 + l] = ap;
        if (w == 0) ownF[l] = xsumIn[p * 64 + l];
        __syncthreads();
        if (tid < 64) {
            float s = 0.f;
            #pragma unroll
            for (int ww = 0; ww < 8; ww++) s += aggP[ww * 64 + tid];
            aggP[tid] = s;
        }
        __syncthreads();
        int c = tid & 63, kc = tid >> 6;
        float op = 0.f;
        #pragma unroll
        for (int kk = 0; kk < 8; kk++) {
            int k = kc * 8 + kk;
            op += WrT[k * 64 + c] * aggP[k] + WtT[k * 64 + c] * ownF[k];
        }
        oP[kc * 64 + c] = op;
        __syncthreads();
        if (tid < 64) {
            float o = brS[tid];
            #pragma unroll
            for (int kk = 0; kk < 8; kk++) o += oP[kk * 64 + tid];
            h2out[p * 64 + tid] = o;
            int rep = p & 31;
            atomicAdd(&statsS[rep * 128 + tid], o);
            atomicAdd(&statsS[rep * 128 + 64 + tid], o * o);
        }
    }
#undef GATH1
#undef DO_CHUNK
}

// ---- xsum[n] = smean over subgraphs of transform(h1) (or x at mode 0) ------
// R8 structure; h1 reads now at non-pow2 slab stride H1S (channel de-aliased).
__global__ __launch_bounds__(1024) void xsum_kernel(
    const float* __restrict__ xsrc, const _Float16* __restrict__ h1prev,
    const float* __restrict__ h2,
    const float* __restrict__ stB, const float* __restrict__ stS,
    const float* __restrict__ gB, const float* __restrict__ bB,
    const float* __restrict__ gS, const float* __restrict__ bS,
    int mode, float* __restrict__ xsum)
{
    __shared__ float bnp[256];
    __shared__ float red[16][64];
    int t = threadIdx.x;
    if (mode) {
        if (t < 64) {
            int c = t;
            float sb = 0.f, qb = 0.f, ss = 0.f, qs = 0.f;
            for (int r2 = 0; r2 < 32; r2++) {
                sb += stB[r2 * 128 + c];
                qb += stB[r2 * 128 + 64 + c];
                ss += stS[r2 * 128 + c];
                qs += stS[r2 * 128 + 64 + c];
            }
            float muB = sb * (1.f / 262144.f);
            float varB = qb * (1.f / 262144.f) - muB * muB;
            float scB = gB[c] * rsqrtf(varB + 1e-5f);
            bnp[c] = scB;
            bnp[64 + c] = bB[c] - muB * scB;
            float muS = ss * (1.f / 512.f);
            float varS = qs * (1.f / 512.f) - muS * muS;
            float scS = gS[c] * rsqrtf(varS + 1e-5f);
            bnp[128 + c] = scS;
            bnp[192 + c] = bS[c] - muS * scS;
        }
        __syncthreads();
    }

    int w = t >> 6;
    int l = t & 63;
    int c4 = (l & 15) * 4;
    int r = l >> 4;
    int n = blockIdx.x;

    float bx = 0.f, by = 0.f, bz = 0.f, bw = 0.f;
    float4 sB = make_float4(1.f, 1.f, 1.f, 1.f);
    float4 hB = make_float4(0.f, 0.f, 0.f, 0.f);
    if (mode) {
        sB = *(const float4*)(bnp + c4);
        hB = *(const float4*)(bnp + 64 + c4);
        float4 sS = *(const float4*)(bnp + 128 + c4);
        float4 hS = *(const float4*)(bnp + 192 + c4);
        float4 b2 = *(const float4*)(h2 + n * 64 + c4);
        bx = b2.x * sS.x + hS.x;
        by = b2.y * sS.y + hS.y;
        bz = b2.z * sS.z + hS.z;
        bw = b2.w * sS.w + hS.w;
    }

    float4 acc = make_float4(0.f, 0.f, 0.f, 0.f);
    #pragma unroll
    for (int j = 0; j < 8; j++) {
        int si = w * 32 + j * 4 + r;
        float4 v;
        if (mode) {
            size_t base = (size_t)si * H1S + (size_t)n * 64 + c4;
            half4v a = *(const half4v*)(h1prev + base);
            v.x = fmaxf((float)a[0] * sB.x + hB.x + bx, 0.f);
            v.y = fmaxf((float)a[1] * sB.y + hB.y + by, 0.f);
            v.z = fmaxf((float)a[2] * sB.z + hB.z + bz, 0.f);
            v.w = fmaxf((float)a[3] * sB.w + hB.w + bw, 0.f);
        } else {
            size_t base = (size_t)(si * 512 + n) * 64 + c4;
            v = *(const float4*)(xsrc + base);
        }
        acc.x += v.x; acc.y += v.y; acc.z += v.z; acc.w += v.w;
    }
    acc.x += __shfl_xor(acc.x, 16, 64); acc.y += __shfl_xor(acc.y, 16, 64);
    acc.z += __shfl_xor(acc.z, 16, 64); acc.w += __shfl_xor(acc.w, 16, 64);
    acc.x += __shfl_xor(acc.x, 32, 64); acc.y += __shfl_xor(acc.y, 32, 64);
    acc.z += __shfl_xor(acc.z, 32, 64); acc.w += __shfl_xor(acc.w, 32, 64);
    if (l < 16) {
        red[w][c4 + 0] = acc.x;
        red[w][c4 + 1] = acc.y;
        red[w][c4 + 2] = acc.z;
        red[w][c4 + 3] = acc.w;
    }
    __syncthreads();
    if (t < 64) {
        float tot = 0.f;
        #pragma unroll
        for (int ww = 0; ww < 16; ww++) tot += red[ww][t];
        xsum[n * 64 + t] = tot * (1.f / 512.f);
    }
}

// ---------------- head ----------------
__global__ void head_kernel(const float* __restrict__ xs, const float* __restrict__ W1,
                            const float* __restrict__ b1, const float* __restrict__ W2,
                            const float* __restrict__ b2, float* __restrict__ out) {
    __shared__ float z[64];
    __shared__ float hid[128];
    int t = threadIdx.x;
    int n = blockIdx.x;
    if (t < 64) {
        float v = xs[n * 64 + t];
        float m = v;
        for (int off = 32; off >= 1; off >>= 1) m = fmaxf(m, __shfl_xor(m, off, 64));
        float e = expf(v - m);
        float s = e;
        for (int off = 32; off >= 1; off >>= 1) s += __shfl_xor(s, off, 64);
        z[t] = v - m - logf(s);
    }
    __syncthreads();
    {
        float acc = b1[t];
        const float* wrow = W1 + t * 64;
        #pragma unroll 8
        for (int k = 0; k < 64; k++) acc += z[k] * wrow[k];
        hid[t] = fmaxf(acc, 0.f);
    }
    __syncthreads();
    if (t < 10) {
        float o = b2[t];
        const float* wrow = W2 + t * 128;
        #pragma unroll 8
        for (int j = 0; j < 128; j++) o += hid[j] * wrow[j];
        out[n * 10 + t] = o;
    }
}

extern "C" void kernel_launch(void* const* d_in, const int* in_sizes, int n_in,
                              void* d_out, int out_size, void* d_ws, size_t ws_size,
                              hipStream_t stream) {
    const float* x       = (const float*)d_in[0];
    const float* Wrel    = (const float*)d_in[1];
    const float* brel    = (const float*)d_in[2];
    const float* Wroot   = (const float*)d_in[3];
    const float* bn_g    = (const float*)d_in[4];
    const float* bn_b    = (const float*)d_in[5];
    const float* Wrel_s  = (const float*)d_in[6];
    const float* brel_s  = (const float*)d_in[7];
    const float* Wroot_s = (const float*)d_in[8];
    const float* bns_g   = (const float*)d_in[9];
    const float* bns_b   = (const float*)d_in[10];
    const float* W1      = (const float*)d_in[11];
    const float* b1      = (const float*)d_in[12];
    const float* W2      = (const float*)d_in[13];
    const float* b2      = (const float*)d_in[14];
    const int* ei        = (const int*)d_in[15];
    const int* oei       = (const int*)d_in[16];
    float* out = (float*)d_out;

    char* ws = (char*)d_ws;
    size_t off = 0;
    auto alloc = [&](size_t bytes) -> void* {
        void* p = ws + off;
        off = (off + bytes + 255) & ~(size_t)255;
        return p;
    };
    _Float16* h1b = (_Float16*)alloc((size_t)NS * H1S * 2);  // padded fp16 h1 (34 MB)
    float* xsum  = (float*)alloc(NS * 64 * 4);
    float* h2buf = (float*)alloc((size_t)2 * NS * 64 * 4);   // ping-pong
    float* stats = (float*)alloc(NLAYER * 2 * 4096 * 4);
    int* rowptr  = (int*)alloc((size_t)NS * 513 * 4);
    int* gcur    = (int*)alloc(8 * 512 * 4);
    unsigned short* ebuf = (unsigned short*)alloc((size_t)NS * EREG * 2);
    int* rowptrS = (int*)alloc(513 * 4);
    int* srcsS   = (int*)alloc(EO * 4);
    float* wrTs  = (float*)alloc(NLAYER * 4096 * 4);
    float* wtTs  = (float*)alloc(NLAYER * 4096 * 4);
    // rbuf (bucketed records) aliases h1b: consumed by csr_sub before layer 0
    unsigned* rbuf = (unsigned*)h1b;   // needs 512*8*BSL*4 = 11.5 MB < 34 MB
    (void)ws_size; (void)in_sizes; (void)n_in; (void)out_size;

    hipMemsetAsync(gcur, 0, 8 * 512 * 4, stream);
    hipMemsetAsync(stats, 0, (size_t)NLAYER * 2 * 4096 * 4, stream);

    bucket_kernel<<<ES / 4096, 256, 0, stream>>>(ei, gcur, rbuf);
    csr_sub_kernel<<<NS, 512, 0, stream>>>(gcur, rbuf, rowptr, ebuf);
    small_csr_kernel<<<1, 1024, 0, stream>>>(oei, rowptrS, srcsS,
                                             Wrel_s, Wroot_s, wrTs, wtTs);

    // fp32 window: 513*68 + 256 floats = 140548 B -> 1 block/CU
    const size_t SMEM = (513 * WROW + 256) * 4;

    for (int i = 0; i < NLAYER; i++) {
        int mode = (i > 0);
        const float* h2R = h2buf + (size_t)((i - 1) & 1) * NS * 64;  // prev (i>0)
        float* h2W = h2buf + (size_t)(i & 1) * NS * 64;
        const float* stPB = stats + (i - 1) * 8192;        // prev layer stats
        const float* stPS = stPB + 4096;
        const float* gBp = bn_g + (i - 1) * 64;
        const float* bBp = bn_b + (i - 1) * 64;
        const float* gSp = bns_g + (i - 1) * 64;
        const float* bSp = bns_b + (i - 1) * 64;
        float* stB = stats + i * 8192;
        float* stS = stB + 4096;

        xsum_kernel<<<NS, 1024, 0, stream>>>(x, h1b, h2R, stPB, stPS,
                                             gBp, bBp, gSp, bSp, mode, xsum);
        gconv_sub_kernel<<<NS, 512, SMEM, stream>>>(x, h1b, h2R, stPB, stPS,
            gBp, bBp, gSp, bSp, mode, rowptr, ebuf,
            Wrel + i * 4096, Wroot + i * 4096, brel + i * 64, h1b, stB,
            xsum, rowptrS, srcsS,
            wrTs + i * 4096, wtTs + i * 4096, brel_s + i * 64, h2W, stS);
    }
    // final xsum = smean(h_final) from h1(3), stats(3), h2(3)
    {
        const float* stPB = stats + 3 * 8192;
        const float* stPS = stPB + 4096;
        const float* h2R = h2buf + (size_t)(3 & 1) * NS * 64;
        xsum_kernel<<<NS, 1024, 0, stream>>>(x, h1b, h2R, stPB, stPS,
            bn_g + 3 * 64, bn_b + 3 * 64, bns_g + 3 * 64, bns_b + 3 * 64, 1, xsum);
    }
    head_kernel<<<NS, 128, 0, stream>>>(xsum, W1, b1, W2, b2, out);
}